// Round 10
// baseline (161.851 us; speedup 1.0000x reference)
//
#include <hip/hip_runtime.h>
#include <hip/hip_bf16.h>

#define IW    4096
#define OW    4096
#define PC    64
#define BATCH 1024
#define BQ    256          // batch-quarter: 2MB contiguous block per quarter

typedef unsigned int u32x4 __attribute__((ext_vector_type(4)));

__device__ __forceinline__ float sigmoidf_(float x) {
    return 1.0f / (1.0f + __expf(-x));
}

__device__ __forceinline__ unsigned short f2bfbits(float f) {
    union { __hip_bfloat16 h; unsigned short u; } cv;
    cv.h = __float2bfloat16(f);   // RNE
    return cv.u;
}

// K1: x [BATCH][IW] f32 -> xT quarter-major: xT[q][IW][BQ] bf16.
__global__ __launch_bounds__(256) void k_transpose_cast(
        const float* __restrict__ x, unsigned short* __restrict__ xT) {
    __shared__ float tile[64][65];          // [c_local][b_local], +1 pad
    const int c0   = blockIdx.x * 64;       // input-width tile
    const int b0   = blockIdx.y * 64;       // batch tile
    const int q    = b0 >> 8;               // quarter
    const int brem = b0 & (BQ - 1);         // batch offset within quarter
    const int t  = threadIdx.x;
    const int r  = t >> 4;                  // 0..15
    const int s  = t & 15;                  // 0..15
    #pragma unroll
    for (int it = 0; it < 4; ++it) {
        const int row = r + 16 * it;        // batch row in tile
        const float4 v = *reinterpret_cast<const float4*>(
            x + (size_t)(b0 + row) * IW + c0 + s * 4);
        tile[s * 4 + 0][row] = v.x;
        tile[s * 4 + 1][row] = v.y;
        tile[s * 4 + 2][row] = v.z;
        tile[s * 4 + 3][row] = v.w;
    }
    __syncthreads();
    unsigned short* dst = xT + (size_t)q * IW * BQ;
    #pragma unroll
    for (int it = 0; it < 4; ++it) {
        const int c = r + 16 * it;          // c_local
        ushort4 o;
        o.x = f2bfbits(tile[c][s * 4 + 0]);
        o.y = f2bfbits(tile[c][s * 4 + 1]);
        o.z = f2bfbits(tile[c][s * 4 + 2]);
        o.w = f2bfbits(tile[c][s * 4 + 3]);
        *reinterpret_cast<ushort4*>(dst + (size_t)(c0 + c) * BQ + brem + s * 4) = o;
    }
}

// K2: 1024 blocks, XCD-pinned quarters (bid&7 -> quarter (bid&7)&3), block
// covers 16 outputs (bijective rank mapping as before).
// ENGINE v3: split-wave dwordx4 gather, NONTEMPORAL loads (bypass L1
// allocation thrash), 4-deep output interleave per wave (4 independent load
// streams in flight). Lanes 0-31 even-p rows, 32-63 odd-p; one load covers
// two 512B row-quarters. __shfl_xor(32) recombines halves at the end.
__global__ __launch_bounds__(256) void k_gather(
        const unsigned short* __restrict__ xT,
        const int* __restrict__ sel,
        const float* __restrict__ wts,
        const float* __restrict__ biases,
        unsigned short* __restrict__ outT) {
    __shared__ int   s_off[16][PC];
    __shared__ float s_wa[16][PC];
    const int bid = blockIdx.x;
    const int xcd = bid & 7;
    const int q   = xcd & 3;                          // this XCD's quarter
    const int g   = ((bid >> 3) << 1) + (xcd >> 2);   // 0..255
    const int t   = threadIdx.x;
    // Stage params for the block's 16 outputs: 1024 entries, 4 per thread.
    #pragma unroll
    for (int r = 0; r < 4; ++r) {
        const int e  = t + 256 * r;
        const int oi = e >> 6;
        const int p  = e & 63;
        const int gi = (g * 16 + oi) * PC + p;
        s_off[oi][p] = sel[gi] * (BQ * 2);            // row byte offset in quarter
        s_wa[oi][p]  = sigmoidf_(wts[gi]);
    }
    __syncthreads();
    const int wv   = t >> 6;
    const int lane = t & 63;
    const int half = lane >> 5;                       // 0: even p, 1: odd p
    const int l31  = lane & 31;
    const int bq   = q * BQ;
    // per-lane base: quarter base + 16B column slot within each row
    const char* baseq = (const char*)xT + (size_t)q * (IW * BQ * 2) + (size_t)l31 * 16;
    const int o0 = wv * 4;                            // this wave's 4 outputs
    float a[4][8] = {};
    #pragma unroll 2
    for (int p2 = 0; p2 < PC / 2; ++p2) {
        #pragma unroll
        for (int j = 0; j < 4; ++j) {
            const int2   offs = *reinterpret_cast<const int2*>(&s_off[o0 + j][2 * p2]);
            const float2 wsp  = *reinterpret_cast<const float2*>(&s_wa[o0 + j][2 * p2]);
            const int   off = half ? offs.y : offs.x;
            const float wj  = half ? wsp.y  : wsp.x;
            const u32x4 r = __builtin_nontemporal_load(
                reinterpret_cast<const u32x4*>(baseq + off));
            a[j][0] = fmaf(wj, __uint_as_float(r.x << 16),         a[j][0]);
            a[j][1] = fmaf(wj, __uint_as_float(r.x & 0xffff0000u), a[j][1]);
            a[j][2] = fmaf(wj, __uint_as_float(r.y << 16),         a[j][2]);
            a[j][3] = fmaf(wj, __uint_as_float(r.y & 0xffff0000u), a[j][3]);
            a[j][4] = fmaf(wj, __uint_as_float(r.z << 16),         a[j][4]);
            a[j][5] = fmaf(wj, __uint_as_float(r.z & 0xffff0000u), a[j][5]);
            a[j][6] = fmaf(wj, __uint_as_float(r.w << 16),         a[j][6]);
            a[j][7] = fmaf(wj, __uint_as_float(r.w & 0xffff0000u), a[j][7]);
        }
    }
    // recombine even-p (lanes 0-31) with odd-p (lanes 32-63) partials
    #pragma unroll
    for (int j = 0; j < 4; ++j)
        #pragma unroll
        for (int k = 0; k < 8; ++k)
            a[j][k] += __shfl_xor(a[j][k], 32);
    const int k0 = half * 4;  // lane (half,l31) owns batches l31*8 + half*4 ..+3
    #pragma unroll
    for (int j = 0; j < 4; ++j) {
        const int oG = g * 16 + o0 + j;
        const float bo = biases[oG];
        ushort4 ov;
        ov.x = f2bfbits(sigmoidf_(a[j][k0 + 0] - bo));
        ov.y = f2bfbits(sigmoidf_(a[j][k0 + 1] - bo));
        ov.z = f2bfbits(sigmoidf_(a[j][k0 + 2] - bo));
        ov.w = f2bfbits(sigmoidf_(a[j][k0 + 3] - bo));
        *reinterpret_cast<ushort4*>(outT + (size_t)oG * BATCH + bq + l31 * 8 + k0) = ov;
    }
}

// K3: outT [OW][BATCH] bf16 -> out [BATCH][OW] f32 (tiled transpose + cast)
__global__ __launch_bounds__(256) void k_transpose_out(
        const unsigned short* __restrict__ outT, float* __restrict__ out) {
    __shared__ float tile[64][65];          // [o_local][b_local]
    const int o0 = blockIdx.x * 64;
    const int b0 = blockIdx.y * 64;
    const int t  = threadIdx.x;
    const int r  = t >> 4;
    const int s  = t & 15;
    #pragma unroll
    for (int it = 0; it < 4; ++it) {
        const int ol = r + 16 * it;
        const ushort4 v = *reinterpret_cast<const ushort4*>(
            outT + (size_t)(o0 + ol) * BATCH + b0 + s * 4);
        tile[ol][s * 4 + 0] = __uint_as_float((unsigned)v.x << 16);
        tile[ol][s * 4 + 1] = __uint_as_float((unsigned)v.y << 16);
        tile[ol][s * 4 + 2] = __uint_as_float((unsigned)v.z << 16);
        tile[ol][s * 4 + 3] = __uint_as_float((unsigned)v.w << 16);
    }
    __syncthreads();
    #pragma unroll
    for (int it = 0; it < 4; ++it) {
        const int bl = r + 16 * it;
        float4 v;
        v.x = tile[s * 4 + 0][bl];
        v.y = tile[s * 4 + 1][bl];
        v.z = tile[s * 4 + 2][bl];
        v.w = tile[s * 4 + 3][bl];
        *reinterpret_cast<float4*>(out + (size_t)(b0 + bl) * OW + o0 + s * 4) = v;
    }
}

// Fallback (correctness-only) if ws is too small for staging.
__global__ __launch_bounds__(256) void k_naive(
        const float* __restrict__ x, const int* __restrict__ sel,
        const float* __restrict__ w, const float* __restrict__ biases,
        float* __restrict__ out) {
    __shared__ int   s_idx[PC];
    __shared__ float s_wa[PC];
    const int o = blockIdx.x;
    const int t = threadIdx.x;
    if (t < PC) {
        s_idx[t] = sel[o * PC + t];
        s_wa[t]  = sigmoidf_(w[o * PC + t]);
    }
    __syncthreads();
    const int b4 = t * 4;
    float a[4] = {0.f, 0.f, 0.f, 0.f};
    for (int p = 0; p < PC; ++p) {
        const int   idx = s_idx[p];
        const float wa  = s_wa[p];
        #pragma unroll
        for (int k = 0; k < 4; ++k)
            a[k] = fmaf(wa, x[(size_t)(b4 + k) * IW + idx], a[k]);
    }
    const float bo = biases[o];
    #pragma unroll
    for (int k = 0; k < 4; ++k)
        out[(size_t)(b4 + k) * OW + o] = sigmoidf_(a[k] - bo);
}

extern "C" void kernel_launch(void* const* d_in, const int* in_sizes, int n_in,
                              void* d_out, int out_size, void* d_ws, size_t ws_size,
                              hipStream_t stream) {
    const float* x      = (const float*)d_in[0];
    const int*   sel    = (const int*)d_in[1];
    const float* w      = (const float*)d_in[2];
    const float* biases = (const float*)d_in[3];
    float*       out    = (float*)d_out;

    const size_t xT_bytes   = (size_t)IW * BATCH * 2;   // 8 MB
    const size_t outT_bytes = (size_t)OW * BATCH * 2;   // 8 MB

    if (ws_size >= xT_bytes + outT_bytes) {
        unsigned short* xT   = (unsigned short*)d_ws;
        unsigned short* outT = (unsigned short*)((char*)d_ws + xT_bytes);
        k_transpose_cast<<<dim3(IW / 64, BATCH / 64), 256, 0, stream>>>(x, xT);
        k_gather<<<dim3(1024), 256, 0, stream>>>(xT, sel, w, biases, outT);
        k_transpose_out<<<dim3(OW / 64, BATCH / 64), 256, 0, stream>>>(outT, out);
    } else {
        k_naive<<<OW, 256, 0, stream>>>(x, sel, w, biases, out);
    }
}

// Round 11
// 106.555 us; speedup vs baseline: 1.5189x; 1.5189x over previous
//
#include <hip/hip_runtime.h>
#include <hip/hip_bf16.h>

#define IW    4096
#define OW    4096
#define PC    64
#define BATCH 1024
#define BQ    256          // batch-quarter: 2MB contiguous block per quarter

__device__ __forceinline__ float sigmoidf_(float x) {
    return 1.0f / (1.0f + __expf(-x));
}

__device__ __forceinline__ unsigned short f2bfbits(float f) {
    union { __hip_bfloat16 h; unsigned short u; } cv;
    cv.h = __float2bfloat16(f);   // RNE
    return cv.u;
}

// K1: x [BATCH][IW] f32 -> xT quarter-major: xT[q][IW][BQ] bf16.
__global__ __launch_bounds__(256) void k_transpose_cast(
        const float* __restrict__ x, unsigned short* __restrict__ xT) {
    __shared__ float tile[64][65];          // [c_local][b_local], +1 pad
    const int c0   = blockIdx.x * 64;       // input-width tile
    const int b0   = blockIdx.y * 64;       // batch tile
    const int q    = b0 >> 8;               // quarter
    const int brem = b0 & (BQ - 1);         // batch offset within quarter
    const int t  = threadIdx.x;
    const int r  = t >> 4;                  // 0..15
    const int s  = t & 15;                  // 0..15
    #pragma unroll
    for (int it = 0; it < 4; ++it) {
        const int row = r + 16 * it;        // batch row in tile
        const float4 v = *reinterpret_cast<const float4*>(
            x + (size_t)(b0 + row) * IW + c0 + s * 4);
        tile[s * 4 + 0][row] = v.x;
        tile[s * 4 + 1][row] = v.y;
        tile[s * 4 + 2][row] = v.z;
        tile[s * 4 + 3][row] = v.w;
    }
    __syncthreads();
    unsigned short* dst = xT + (size_t)q * IW * BQ;
    #pragma unroll
    for (int it = 0; it < 4; ++it) {
        const int c = r + 16 * it;          // c_local
        ushort4 o;
        o.x = f2bfbits(tile[c][s * 4 + 0]);
        o.y = f2bfbits(tile[c][s * 4 + 1]);
        o.z = f2bfbits(tile[c][s * 4 + 2]);
        o.w = f2bfbits(tile[c][s * 4 + 3]);
        *reinterpret_cast<ushort4*>(dst + (size_t)(c0 + c) * BQ + brem + s * 4) = o;
    }
}

// K2 (fused): 1024 blocks, XCD-pinned quarters; block covers 16 outputs x
// one 256-batch quarter. Gather engine identical to the proven round-7
// version (split-wave dwordx4, 2-output interleave, NORMAL loads).
// NEW: epilogue stages the 16x256 f32 output tile in LDS and writes
// out[b][o0:o15] directly (64B row-chunks) -- kills the outT buffer and
// the separate K3 transpose kernel entirely.
__global__ __launch_bounds__(256) void k_gather_fused(
        const unsigned short* __restrict__ xT,
        const int* __restrict__ sel,
        const float* __restrict__ wts,
        const float* __restrict__ biases,
        float* __restrict__ out) {
    __shared__ int   s_off[16][PC];
    __shared__ float s_wa[16][PC];
    __shared__ float otile[16][BQ + 4];               // 16 outputs x 256 batches, padded
    const int bid = blockIdx.x;
    const int xcd = bid & 7;
    const int q   = xcd & 3;                          // this XCD's quarter
    const int g   = ((bid >> 3) << 1) + (xcd >> 2);   // 0..255
    const int t   = threadIdx.x;
    // Stage params for the block's 16 outputs: 1024 entries, 4 per thread.
    #pragma unroll
    for (int r = 0; r < 4; ++r) {
        const int e  = t + 256 * r;
        const int oi = e >> 6;
        const int p  = e & 63;
        const int gi = (g * 16 + oi) * PC + p;
        s_off[oi][p] = sel[gi] * (BQ * 2);            // row byte offset in quarter
        s_wa[oi][p]  = sigmoidf_(wts[gi]);
    }
    __syncthreads();
    const int wv   = t >> 6;
    const int lane = t & 63;
    const int half = lane >> 5;                       // 0: even p, 1: odd p
    const int l31  = lane & 31;
    const int bq   = q * BQ;
    // per-lane base: quarter base + 16B column slot within each row
    const char* baseq = (const char*)xT + (size_t)q * (IW * BQ * 2) + (size_t)l31 * 16;
    #pragma unroll
    for (int pass = 0; pass < 2; ++pass) {
        const int oA = wv * 4 + pass * 2;             // local output 0..15
        const int oB = oA + 1;
        float a[8] = {0.f,0.f,0.f,0.f,0.f,0.f,0.f,0.f};
        float b[8] = {0.f,0.f,0.f,0.f,0.f,0.f,0.f,0.f};
        #pragma unroll 4
        for (int p2 = 0; p2 < PC / 2; ++p2) {
            // uniform pair reads (LDS broadcast)
            const int2   offsA = *reinterpret_cast<const int2*>(&s_off[oA][2 * p2]);
            const int2   offsB = *reinterpret_cast<const int2*>(&s_off[oB][2 * p2]);
            const float2 wsA   = *reinterpret_cast<const float2*>(&s_wa[oA][2 * p2]);
            const float2 wsB   = *reinterpret_cast<const float2*>(&s_wa[oB][2 * p2]);
            const int   offA = half ? offsA.y : offsA.x;
            const int   offB = half ? offsB.y : offsB.x;
            const float wA   = half ? wsA.y   : wsA.x;
            const float wB   = half ? wsB.y   : wsB.x;
            const uint4 rA = *reinterpret_cast<const uint4*>(baseq + offA);
            const uint4 rB = *reinterpret_cast<const uint4*>(baseq + offB);
            a[0] = fmaf(wA, __uint_as_float(rA.x << 16),         a[0]);
            a[1] = fmaf(wA, __uint_as_float(rA.x & 0xffff0000u), a[1]);
            a[2] = fmaf(wA, __uint_as_float(rA.y << 16),         a[2]);
            a[3] = fmaf(wA, __uint_as_float(rA.y & 0xffff0000u), a[3]);
            a[4] = fmaf(wA, __uint_as_float(rA.z << 16),         a[4]);
            a[5] = fmaf(wA, __uint_as_float(rA.z & 0xffff0000u), a[5]);
            a[6] = fmaf(wA, __uint_as_float(rA.w << 16),         a[6]);
            a[7] = fmaf(wA, __uint_as_float(rA.w & 0xffff0000u), a[7]);
            b[0] = fmaf(wB, __uint_as_float(rB.x << 16),         b[0]);
            b[1] = fmaf(wB, __uint_as_float(rB.x & 0xffff0000u), b[1]);
            b[2] = fmaf(wB, __uint_as_float(rB.y << 16),         b[2]);
            b[3] = fmaf(wB, __uint_as_float(rB.y & 0xffff0000u), b[3]);
            b[4] = fmaf(wB, __uint_as_float(rB.z << 16),         b[4]);
            b[5] = fmaf(wB, __uint_as_float(rB.z & 0xffff0000u), b[5]);
            b[6] = fmaf(wB, __uint_as_float(rB.w << 16),         b[6]);
            b[7] = fmaf(wB, __uint_as_float(rB.w & 0xffff0000u), b[7]);
        }
        // recombine even-p (lanes 0-31) with odd-p (lanes 32-63) partials
        #pragma unroll
        for (int k = 0; k < 8; ++k) {
            a[k] += __shfl_xor(a[k], 32);
            b[k] += __shfl_xor(b[k], 32);
        }
        const float biasA = biases[g * 16 + oA];
        const float biasB = biases[g * 16 + oB];
        // lane (half,l31) owns batches l31*8 + half*4 .. +3
        const int k0 = half * 4;
        const int bl = l31 * 8 + k0;
        float4 fa, fb;
        fa.x = sigmoidf_(a[k0 + 0] - biasA);
        fa.y = sigmoidf_(a[k0 + 1] - biasA);
        fa.z = sigmoidf_(a[k0 + 2] - biasA);
        fa.w = sigmoidf_(a[k0 + 3] - biasA);
        fb.x = sigmoidf_(b[k0 + 0] - biasB);
        fb.y = sigmoidf_(b[k0 + 1] - biasB);
        fb.z = sigmoidf_(b[k0 + 2] - biasB);
        fb.w = sigmoidf_(b[k0 + 3] - biasB);
        *reinterpret_cast<float4*>(&otile[oA][bl]) = fa;
        *reinterpret_cast<float4*>(&otile[oB][bl]) = fb;
    }
    __syncthreads();
    // write-out: thread t = batch b_local; out[bq+t][g*16 .. +15] = 64B
    {
        const int o0 = g * 16;
        float4 v0, v1, v2, v3;
        v0.x = otile[ 0][t]; v0.y = otile[ 1][t]; v0.z = otile[ 2][t]; v0.w = otile[ 3][t];
        v1.x = otile[ 4][t]; v1.y = otile[ 5][t]; v1.z = otile[ 6][t]; v1.w = otile[ 7][t];
        v2.x = otile[ 8][t]; v2.y = otile[ 9][t]; v2.z = otile[10][t]; v2.w = otile[11][t];
        v3.x = otile[12][t]; v3.y = otile[13][t]; v3.z = otile[14][t]; v3.w = otile[15][t];
        float* dst = out + (size_t)(bq + t) * OW + o0;
        *reinterpret_cast<float4*>(dst +  0) = v0;
        *reinterpret_cast<float4*>(dst +  4) = v1;
        *reinterpret_cast<float4*>(dst +  8) = v2;
        *reinterpret_cast<float4*>(dst + 12) = v3;
    }
}

// Fallback (correctness-only) if ws is too small for staging.
__global__ __launch_bounds__(256) void k_naive(
        const float* __restrict__ x, const int* __restrict__ sel,
        const float* __restrict__ w, const float* __restrict__ biases,
        float* __restrict__ out) {
    __shared__ int   s_idx[PC];
    __shared__ float s_wa[PC];
    const int o = blockIdx.x;
    const int t = threadIdx.x;
    if (t < PC) {
        s_idx[t] = sel[o * PC + t];
        s_wa[t]  = sigmoidf_(w[o * PC + t]);
    }
    __syncthreads();
    const int b4 = t * 4;
    float a[4] = {0.f, 0.f, 0.f, 0.f};
    for (int p = 0; p < PC; ++p) {
        const int   idx = s_idx[p];
        const float wa  = s_wa[p];
        #pragma unroll
        for (int k = 0; k < 4; ++k)
            a[k] = fmaf(wa, x[(size_t)(b4 + k) * IW + idx], a[k]);
    }
    const float bo = biases[o];
    #pragma unroll
    for (int k = 0; k < 4; ++k)
        out[(size_t)(b4 + k) * OW + o] = sigmoidf_(a[k] - bo);
}

extern "C" void kernel_launch(void* const* d_in, const int* in_sizes, int n_in,
                              void* d_out, int out_size, void* d_ws, size_t ws_size,
                              hipStream_t stream) {
    const float* x      = (const float*)d_in[0];
    const int*   sel    = (const int*)d_in[1];
    const float* w      = (const float*)d_in[2];
    const float* biases = (const float*)d_in[3];
    float*       out    = (float*)d_out;

    const size_t xT_bytes = (size_t)IW * BATCH * 2;   // 8 MB

    if (ws_size >= xT_bytes) {
        unsigned short* xT = (unsigned short*)d_ws;
        k_transpose_cast<<<dim3(IW / 64, BATCH / 64), 256, 0, stream>>>(x, xT);
        k_gather_fused<<<dim3(1024), 256, 0, stream>>>(xT, sel, w, biases, out);
    } else {
        k_naive<<<OW, 256, 0, stream>>>(x, sel, w, biases, out);
    }
}